// Round 5
// baseline (314.683 us; speedup 1.0000x reference)
//
#include <hip/hip_runtime.h>

#define NN 10000      // nodes
#define NNPAD 10112   // padded to 79*128
#define NE 160000     // edges
#define HF 512        // hidden/in features
#define LL 6          // layers
#define NC 64         // classes
#define KCAT (LL*HF)  // 3072
#define BN_EPS 1e-5f
#define CHUNK 128     // agg feature chunk (4 chunks, 2 XCDs each)

typedef _Float16 f16x8 __attribute__((ext_vector_type(8)));
typedef _Float16 f16x4 __attribute__((ext_vector_type(4)));
typedef float f32x4 __attribute__((ext_vector_type(4)));

#define GLB(p) ((const __attribute__((address_space(1))) void*)(p))
#define LDSP(p) ((__attribute__((address_space(3))) void*)(p))

// ---------------- setup kernels ----------------

__global__ void zero_u32_kernel(unsigned* __restrict__ p, int n) {
  int i = blockIdx.x * blockDim.x + threadIdx.x;
  if (i < n) p[i] = 0u;
}

__global__ void deg_kernel(const int* __restrict__ src, const int* __restrict__ dst,
                           unsigned* __restrict__ cnt_out, unsigned* __restrict__ cnt_in) {
  int e = blockIdx.x * blockDim.x + threadIdx.x;
  if (e < NE) {
    atomicAdd(&cnt_out[src[e]], 1u);
    atomicAdd(&cnt_in[dst[e]], 1u);
  }
}

__global__ void norm_kernel(const unsigned* __restrict__ cnt_out, const unsigned* __restrict__ cnt_in,
                            float* __restrict__ norm_src, float* __restrict__ norm_dst) {
  int i = blockIdx.x * blockDim.x + threadIdx.x;
  if (i < NN) {
    unsigned co = cnt_out[i]; if (co < 1u) co = 1u;
    unsigned ci = cnt_in[i];  if (ci < 1u) ci = 1u;
    norm_src[i] = rsqrtf((float)co);
    norm_dst[i] = rsqrtf((float)ci);
  }
}

// exclusive scan of cnt[0..NN) -> off[0..NN], single block of 1024
__global__ void scan_kernel(const unsigned* __restrict__ cnt, unsigned* __restrict__ off) {
  __shared__ unsigned wsum[16];
  int tid = threadIdx.x;
  int lane = tid & 63, wid = tid >> 6;
  unsigned base = 0;
  for (int c = 0; c < NN; c += 1024) {
    int i = c + tid;
    unsigned v = (i < NN) ? cnt[i] : 0u;
    unsigned x = v;
    #pragma unroll
    for (int d = 1; d < 64; d <<= 1) {
      unsigned y = __shfl_up(x, d, 64);
      if (lane >= d) x += y;
    }
    if (lane == 63) wsum[wid] = x;
    __syncthreads();
    if (wid == 0 && lane < 16) {
      unsigned s = wsum[lane];
      #pragma unroll
      for (int d = 1; d < 16; d <<= 1) {
        unsigned y = __shfl_up(s, d, 16);
        if (lane >= d) s += y;
      }
      wsum[lane] = s;
    }
    __syncthreads();
    unsigned wbase = wid ? wsum[wid - 1] : 0u;
    if (i < NN) off[i] = base + wbase + x - v;
    unsigned tot = wsum[15];
    __syncthreads();
    base += tot;
  }
  if (tid == 0) off[NN] = base;
}

__global__ void fill_kernel(const int* __restrict__ src, const int* __restrict__ dst,
                            const unsigned* __restrict__ off, unsigned* __restrict__ cursor,
                            int* __restrict__ edge_src) {
  int e = blockIdx.x * blockDim.x + threadIdx.x;
  if (e < NE) {
    int d = dst[e];
    unsigned p = atomicAdd(&cursor[d], 1u);
    edge_src[off[d] + p] = src[e];
  }
}

// ---------------- weight convert: W[k][n] fp32 -> Wt[n][k] fp16 ----------------
__global__ void convert_w(const float* __restrict__ W0, const float* __restrict__ Ws,
                          _Float16* __restrict__ Wt) {
  int l = blockIdx.z;
  const float* W = (l == 0) ? W0 : (Ws + (size_t)(l - 1) * HF * HF);
  __shared__ float t[32][33];
  int n0 = blockIdx.x * 32, k0 = blockIdx.y * 32;
  int tx = threadIdx.x & 31, ty4 = (threadIdx.x >> 5) * 4;
  #pragma unroll
  for (int j = 0; j < 4; ++j)
    t[ty4 + j][tx] = W[(size_t)(k0 + ty4 + j) * HF + n0 + tx];
  __syncthreads();
  size_t base = (size_t)l * HF * HF;
  #pragma unroll
  for (int j = 0; j < 4; ++j)
    Wt[base + (size_t)(n0 + ty4 + j) * HF + k0 + tx] = (_Float16)t[tx][ty4 + j];
}

// linW[k][c] fp32 -> Lt[c][k] fp16
__global__ void convert_lin(const float* __restrict__ linW, _Float16* __restrict__ Lt) {
  __shared__ float t[32][33];
  int n0 = blockIdx.x * 32, k0 = blockIdx.y * 32;
  int tx = threadIdx.x & 31, ty4 = (threadIdx.x >> 5) * 4;
  #pragma unroll
  for (int j = 0; j < 4; ++j)
    t[ty4 + j][tx] = linW[(size_t)(k0 + ty4 + j) * NC + n0 + tx];
  __syncthreads();
  #pragma unroll
  for (int j = 0; j < 4; ++j)
    Lt[(size_t)(n0 + ty4 + j) * KCAT + k0 + tx] = (_Float16)t[tx][ty4 + j];
}

// ---------------- x*norm_src -> zh fp16 ----------------
__global__ void split_x(const float* __restrict__ x, const float* __restrict__ nsrc,
                        _Float16* __restrict__ zh) {
  int i = blockIdx.x * blockDim.x + threadIdx.x;   // float4 index
  if (i >= NN * HF / 4) return;
  int base = i * 4;
  int row = base >> 9;
  float ns = nsrc[row];
  float4 v = *(const float4*)&x[base];
  f16x4 h;
  h.x = (_Float16)(v.x * ns);
  h.y = (_Float16)(v.y * ns);
  h.z = (_Float16)(v.z * ns);
  h.w = (_Float16)(v.w * ns);
  *(f16x4*)&zh[base] = h;
}

// ---------------- layer GEMM via MFMA, LDS double-buffered 2-phase ----------------
// 128x128 tile, BK=64, 4 waves (2x2), wave tile 64x64 = 4x4 frags of 16x16x32_f16.
// Stage(t+1) issued BEFORE compute(t); one __syncthreads per K-tile (drains vmcnt+lgkm).
__launch_bounds__(256, 2)
__global__ void gemm_layer_f16(const _Float16* __restrict__ Z,
                               const _Float16* __restrict__ Wt,
                               _Float16* __restrict__ Mout) {
  __shared__ _Float16 As[2][128][64];
  __shared__ _Float16 Bs[2][128][64];
  int m0 = blockIdx.y * 128;
  int n0 = blockIdx.x * 128;
  int wid = threadIdx.x >> 6, lane = threadIdx.x & 63;
  int wr = wid >> 1, wc = wid & 1;
  int fr = lane & 15, kg = lane >> 4;
  int rr = lane >> 3;            // staging row within 8-row group
  int ck = (lane & 7) ^ rr;      // pre-swizzled source chunk

  f32x4 acc[4][4];
  #pragma unroll
  for (int m = 0; m < 4; ++m)
    #pragma unroll
    for (int n = 0; n < 4; ++n)
      acc[m][n] = (f32x4){0.f, 0.f, 0.f, 0.f};

  const _Float16* gA = Z  + (size_t)(m0 + wid * 32 + rr) * HF + ck * 8;
  const _Float16* gB = Wt + (size_t)(n0 + wid * 32 + rr) * HF + ck * 8;

  auto stage = [&](int buf, int k0) {
    #pragma unroll
    for (int i = 0; i < 4; ++i) {
      __builtin_amdgcn_global_load_lds(GLB(gA + (size_t)i * 8 * HF + k0),
                                       LDSP(&As[buf][wid * 32 + i * 8][0]), 16, 0, 0);
      __builtin_amdgcn_global_load_lds(GLB(gB + (size_t)i * 8 * HF + k0),
                                       LDSP(&Bs[buf][wid * 32 + i * 8][0]), 16, 0, 0);
    }
  };

  stage(0, 0);
  __syncthreads();
  int cur = 0;
  for (int t = 0; t < HF / 64; ++t) {
    if (t < HF / 64 - 1) stage(cur ^ 1, (t + 1) * 64);
    #pragma unroll
    for (int kk = 0; kk < 2; ++kk) {
      f16x8 a[4], b[4];
      #pragma unroll
      for (int n = 0; n < 4; ++n) {
        int row = wc * 64 + n * 16 + fr;
        b[n] = *(const f16x8*)&Bs[cur][row][((kk * 4 + kg) ^ (row & 7)) * 8];
      }
      #pragma unroll
      for (int m = 0; m < 4; ++m) {
        int row = wr * 64 + m * 16 + fr;
        a[m] = *(const f16x8*)&As[cur][row][((kk * 4 + kg) ^ (row & 7)) * 8];
      }
      #pragma unroll
      for (int m = 0; m < 4; ++m)
        #pragma unroll
        for (int n = 0; n < 4; ++n)
          acc[m][n] = __builtin_amdgcn_mfma_f32_16x16x32_f16(a[m], b[n], acc[m][n], 0, 0, 0);
    }
    __syncthreads();
    cur ^= 1;
  }
  // C/D layout: col = lane&15, row = (lane>>4)*4 + j
  #pragma unroll
  for (int m = 0; m < 4; ++m) {
    #pragma unroll
    for (int j = 0; j < 4; ++j) {
      int row = m0 + wr * 64 + m * 16 + kg * 4 + j;
      if (row < NN) {
        #pragma unroll
        for (int n = 0; n < 4; ++n) {
          int col = n0 + wc * 64 + n * 16 + fr;
          Mout[(size_t)row * HF + col] = (_Float16)acc[m][n][j];
        }
      }
    }
  }
}

// ---------------- aggregation + norm_dst + bias + BN + ReLU, XCD-chunked ----------------
// 4 feature-chunks of 128; chunk = (blockIdx.x & 7) >> 1 maps each chunk to 2 XCDs
// (round-robin heuristic) so each XCD's gathers touch a 2.6 MB L2-resident slice.
// 32 lanes per node (f16x4 each), 8 nodes per 256-thread block. grid.x = 8*625 = 5000.
__launch_bounds__(256)
__global__ void agg_bn_kernel(const _Float16* __restrict__ Mm,
                              const int* __restrict__ edge_src,
                              const unsigned* __restrict__ row_off,
                              const float* __restrict__ norm_dst,
                              const float* __restrict__ norm_src,
                              const float* __restrict__ bias,
                              const float* __restrict__ gamma,
                              const float* __restrict__ beta,
                              const float* __restrict__ mean,
                              const float* __restrict__ var,
                              _Float16* __restrict__ hcat_col,   // hcat + l*HF, row stride KCAT
                              _Float16* __restrict__ zh) {       // may be null (last layer)
  int slot  = blockIdx.x & 7;
  int chunk = slot >> 1;
  int grp   = blockIdx.x >> 3;             // 0..624
  int n     = grp * 16 + (slot & 1) * 8 + (threadIdx.x >> 5);
  if (n >= NN) return;
  int f = chunk * CHUNK + (threadIdx.x & 31) * 4;
  unsigned e0 = row_off[n], e1 = row_off[n + 1];
  float ax = 0.f, ay = 0.f, az = 0.f, aw = 0.f;
  unsigned e = e0;
  for (; e + 4 <= e1; e += 4) {
    int s0 = edge_src[e], s1 = edge_src[e + 1], s2 = edge_src[e + 2], s3 = edge_src[e + 3];
    f16x4 v0 = *(const f16x4*)&Mm[(size_t)s0 * HF + f];
    f16x4 v1 = *(const f16x4*)&Mm[(size_t)s1 * HF + f];
    f16x4 v2 = *(const f16x4*)&Mm[(size_t)s2 * HF + f];
    f16x4 v3 = *(const f16x4*)&Mm[(size_t)s3 * HF + f];
    ax += (float)v0.x + (float)v1.x + (float)v2.x + (float)v3.x;
    ay += (float)v0.y + (float)v1.y + (float)v2.y + (float)v3.y;
    az += (float)v0.z + (float)v1.z + (float)v2.z + (float)v3.z;
    aw += (float)v0.w + (float)v1.w + (float)v2.w + (float)v3.w;
  }
  for (; e < e1; ++e) {
    int s = edge_src[e];
    f16x4 v = *(const f16x4*)&Mm[(size_t)s * HF + f];
    ax += (float)v.x; ay += (float)v.y; az += (float)v.z; aw += (float)v.w;
  }
  float nd = norm_dst[n];
  float4 b  = *(const float4*)&bias[f];
  float4 g  = *(const float4*)&gamma[f];
  float4 bt = *(const float4*)&beta[f];
  float4 mu = *(const float4*)&mean[f];
  float4 vr = *(const float4*)&var[f];
  float sx = g.x * rsqrtf(vr.x + BN_EPS);
  float sy = g.y * rsqrtf(vr.y + BN_EPS);
  float sz = g.z * rsqrtf(vr.z + BN_EPS);
  float sw = g.w * rsqrtf(vr.w + BN_EPS);
  float yx = fmaxf((ax * nd + b.x - mu.x) * sx + bt.x, 0.f);
  float yy = fmaxf((ay * nd + b.y - mu.y) * sy + bt.y, 0.f);
  float yz = fmaxf((az * nd + b.z - mu.z) * sz + bt.z, 0.f);
  float yw = fmaxf((aw * nd + b.w - mu.w) * sw + bt.w, 0.f);
  f16x4 hv;
  hv.x = (_Float16)yx; hv.y = (_Float16)yy; hv.z = (_Float16)yz; hv.w = (_Float16)yw;
  *(f16x4*)&hcat_col[(size_t)n * KCAT + f] = hv;
  if (zh) {
    float ns = norm_src[n];
    f16x4 zv;
    zv.x = (_Float16)(yx * ns); zv.y = (_Float16)(yy * ns);
    zv.z = (_Float16)(yz * ns); zv.w = (_Float16)(yw * ns);
    *(f16x4*)&zh[(size_t)n * HF + f] = zv;
  }
}

// ---------------- final GEMM via MFMA, split-K over 6 chunks, 2-phase dbuf ----------------
__launch_bounds__(256, 2)
__global__ void final_gemm_f16(const _Float16* __restrict__ Hc,
                               const _Float16* __restrict__ Lt,
                               float* __restrict__ part) {
  __shared__ _Float16 As[2][128][64];
  __shared__ _Float16 Bs[2][64][64];
  int m0 = blockIdx.x * 128;
  int sp = blockIdx.y;
  int kbase = sp * HF;
  int wid = threadIdx.x >> 6, lane = threadIdx.x & 63;
  int fr = lane & 15, kg = lane >> 4;
  int rr = lane >> 3;
  int ck = (lane & 7) ^ rr;

  f32x4 acc[2][4];
  #pragma unroll
  for (int m = 0; m < 2; ++m)
    #pragma unroll
    for (int n = 0; n < 4; ++n)
      acc[m][n] = (f32x4){0.f, 0.f, 0.f, 0.f};

  const _Float16* gA = Hc + (size_t)(m0 + wid * 32 + rr) * KCAT + kbase + ck * 8;
  const _Float16* gB = Lt + (size_t)(wid * 16 + rr) * KCAT + kbase + ck * 8;

  auto stage = [&](int buf, int k0) {
    #pragma unroll
    for (int i = 0; i < 4; ++i)
      __builtin_amdgcn_global_load_lds(GLB(gA + (size_t)i * 8 * KCAT + k0),
                                       LDSP(&As[buf][wid * 32 + i * 8][0]), 16, 0, 0);
    #pragma unroll
    for (int i = 0; i < 2; ++i)
      __builtin_amdgcn_global_load_lds(GLB(gB + (size_t)i * 8 * KCAT + k0),
                                       LDSP(&Bs[buf][wid * 16 + i * 8][0]), 16, 0, 0);
  };

  stage(0, 0);
  __syncthreads();
  int cur = 0;
  for (int t = 0; t < HF / 64; ++t) {
    if (t < HF / 64 - 1) stage(cur ^ 1, (t + 1) * 64);
    #pragma unroll
    for (int kk = 0; kk < 2; ++kk) {
      f16x8 a[2], b[4];
      #pragma unroll
      for (int n = 0; n < 4; ++n) {
        int row = n * 16 + fr;
        b[n] = *(const f16x8*)&Bs[cur][row][((kk * 4 + kg) ^ (row & 7)) * 8];
      }
      #pragma unroll
      for (int m = 0; m < 2; ++m) {
        int row = wid * 32 + m * 16 + fr;
        a[m] = *(const f16x8*)&As[cur][row][((kk * 4 + kg) ^ (row & 7)) * 8];
      }
      #pragma unroll
      for (int m = 0; m < 2; ++m)
        #pragma unroll
        for (int n = 0; n < 4; ++n)
          acc[m][n] = __builtin_amdgcn_mfma_f32_16x16x32_f16(a[m], b[n], acc[m][n], 0, 0, 0);
    }
    __syncthreads();
    cur ^= 1;
  }
  #pragma unroll
  for (int m = 0; m < 2; ++m) {
    #pragma unroll
    for (int j = 0; j < 4; ++j) {
      int row = m0 + wid * 32 + m * 16 + kg * 4 + j;
      if (row < NN) {
        #pragma unroll
        for (int n = 0; n < 4; ++n) {
          int col = n * 16 + fr;
          part[((size_t)sp * NN + row) * NC + col] = acc[m][n][j];
        }
      }
    }
  }
}

__launch_bounds__(256)
__global__ void final_reduce(const float* __restrict__ part,
                             const float* __restrict__ linb,
                             float* __restrict__ out) {
  int i = blockIdx.x * blockDim.x + threadIdx.x;   // float4 index
  if (i >= NN * NC / 4) return;
  int n  = i >> 4;
  int cq = i & 15;
  float4 s = *(const float4*)&linb[cq * 4];
  #pragma unroll
  for (int sp = 0; sp < LL; ++sp) {
    float4 v = *(const float4*)&part[((size_t)sp * NN + n) * NC + cq * 4];
    s.x += v.x; s.y += v.y; s.z += v.z; s.w += v.w;
  }
  *(float4*)&out[(size_t)n * NC + cq * 4] = s;
}

// ---------------- launch ----------------

extern "C" void kernel_launch(void* const* d_in, const int* in_sizes, int n_in,
                              void* d_out, int out_size, void* d_ws, size_t ws_size,
                              hipStream_t stream) {
  const float* x     = (const float*)d_in[0];
  const float* W0    = (const float*)d_in[1];
  const float* Ws    = (const float*)d_in[2];
  const float* bs    = (const float*)d_in[3];
  const float* gamma = (const float*)d_in[4];
  const float* beta  = (const float*)d_in[5];
  const float* rmean = (const float*)d_in[6];
  const float* rvar  = (const float*)d_in[7];
  const float* linW  = (const float*)d_in[8];
  const float* linb  = (const float*)d_in[9];
  const int*   src   = (const int*)d_in[10];
  const int*   dst   = (const int*)d_in[11];
  float* out = (float*)d_out;

  char* w = (char*)d_ws;
  size_t o = 0;
  auto carve = [&](size_t bytes) -> void* {
    o = (o + 255) & ~(size_t)255;
    void* p = w + o;
    o += bytes;
    return p;
  };
  _Float16*  m_buf = (_Float16*)carve((size_t)NNPAD * HF * 2);
  _Float16*  hcat  = (_Float16*)carve((size_t)NNPAD * KCAT * 2);
  _Float16*  zh    = (_Float16*)carve((size_t)NNPAD * HF * 2);
  _Float16*  wt    = (_Float16*)carve((size_t)LL * HF * HF * 2);
  _Float16*  lt    = (_Float16*)carve((size_t)NC * KCAT * 2);
  float*     part  = (float*)carve((size_t)LL * NN * NC * 4);
  float*     nsrc  = (float*)carve((size_t)NN * 4);
  float*     ndst  = (float*)carve((size_t)NN * 4);
  unsigned*  cnts  = (unsigned*)carve((size_t)3 * NN * 4);
  unsigned*  roff  = (unsigned*)carve((size_t)(NN + 1) * 4);
  int*       esrc  = (int*)carve((size_t)NE * 4);

  unsigned* cnt_out = cnts;
  unsigned* cnt_in  = cnts + NN;
  unsigned* cursor  = cnts + 2 * NN;

  zero_u32_kernel<<<(3 * NN + 255) / 256, 256, 0, stream>>>(cnts, 3 * NN);
  deg_kernel<<<(NE + 255) / 256, 256, 0, stream>>>(src, dst, cnt_out, cnt_in);
  norm_kernel<<<(NN + 255) / 256, 256, 0, stream>>>(cnt_out, cnt_in, nsrc, ndst);
  scan_kernel<<<1, 1024, 0, stream>>>(cnt_in, roff);
  fill_kernel<<<(NE + 255) / 256, 256, 0, stream>>>(src, dst, roff, cursor, esrc);
  convert_w<<<dim3(16, 16, 6), 256, 0, stream>>>(W0, Ws, wt);
  convert_lin<<<dim3(2, 96), 256, 0, stream>>>(linW, lt);
  split_x<<<(NN * HF / 4 + 255) / 256, 256, 0, stream>>>(x, nsrc, zh);

  for (int l = 0; l < LL; ++l) {
    gemm_layer_f16<<<dim3(HF / 128, NNPAD / 128), 256, 0, stream>>>(
        zh, wt + (size_t)l * HF * HF, m_buf);
    bool last = (l == LL - 1);
    agg_bn_kernel<<<8 * 625, 256, 0, stream>>>(m_buf, esrc, roff, ndst, nsrc,
                                               bs + l * HF, gamma + l * HF, beta + l * HF,
                                               rmean + l * HF, rvar + l * HF,
                                               hcat + (size_t)l * HF,
                                               last ? nullptr : zh);
  }
  final_gemm_f16<<<dim3(NNPAD / 128, LL), 256, 0, stream>>>(hcat, lt, part);
  final_reduce<<<(NN * NC / 4 + 255) / 256, 256, 0, stream>>>(part, linb, out);
}

// Round 6
// 306.007 us; speedup vs baseline: 1.0284x; 1.0284x over previous
//
#include <hip/hip_runtime.h>

#define NN 10000      // nodes
#define NNPAD 10112   // padded to 79*128
#define NE 160000     // edges
#define HF 512        // hidden/in features
#define LL 6          // layers
#define NC 64         // classes
#define KCAT (LL*HF)  // 3072
#define BN_EPS 1e-5f

typedef _Float16 f16x8 __attribute__((ext_vector_type(8)));
typedef _Float16 f16x4 __attribute__((ext_vector_type(4)));
typedef float f32x4 __attribute__((ext_vector_type(4)));

#define GLB(p) ((const __attribute__((address_space(1))) void*)(p))
#define LDSP(p) ((__attribute__((address_space(3))) void*)(p))

// ---------------- setup kernels ----------------

__global__ void zero_u32_kernel(unsigned* __restrict__ p, int n) {
  int i = blockIdx.x * blockDim.x + threadIdx.x;
  if (i < n) p[i] = 0u;
}

__global__ void deg_kernel(const int* __restrict__ src, const int* __restrict__ dst,
                           unsigned* __restrict__ cnt_out, unsigned* __restrict__ cnt_in) {
  int e = blockIdx.x * blockDim.x + threadIdx.x;
  if (e < NE) {
    atomicAdd(&cnt_out[src[e]], 1u);
    atomicAdd(&cnt_in[dst[e]], 1u);
  }
}

__global__ void norm_kernel(const unsigned* __restrict__ cnt_out, const unsigned* __restrict__ cnt_in,
                            float* __restrict__ norm_src, float* __restrict__ norm_dst) {
  int i = blockIdx.x * blockDim.x + threadIdx.x;
  if (i < NN) {
    unsigned co = cnt_out[i]; if (co < 1u) co = 1u;
    unsigned ci = cnt_in[i];  if (ci < 1u) ci = 1u;
    norm_src[i] = rsqrtf((float)co);
    norm_dst[i] = rsqrtf((float)ci);
  }
}

// BN scale/shift precompute over LL*HF features
__global__ void bn_prep(const float* __restrict__ bs, const float* __restrict__ gamma,
                        const float* __restrict__ beta, const float* __restrict__ rmean,
                        const float* __restrict__ rvar,
                        float* __restrict__ scale, float* __restrict__ shift) {
  int i = blockIdx.x * blockDim.x + threadIdx.x;
  if (i < LL * HF) {
    float s = gamma[i] * rsqrtf(rvar[i] + BN_EPS);
    scale[i] = s;
    shift[i] = (bs[i] - rmean[i]) * s + beta[i];
  }
}

// exclusive scan of cnt[0..NN) -> off[0..NN], single block of 1024
__global__ void scan_kernel(const unsigned* __restrict__ cnt, unsigned* __restrict__ off) {
  __shared__ unsigned wsum[16];
  int tid = threadIdx.x;
  int lane = tid & 63, wid = tid >> 6;
  unsigned base = 0;
  for (int c = 0; c < NN; c += 1024) {
    int i = c + tid;
    unsigned v = (i < NN) ? cnt[i] : 0u;
    unsigned x = v;
    #pragma unroll
    for (int d = 1; d < 64; d <<= 1) {
      unsigned y = __shfl_up(x, d, 64);
      if (lane >= d) x += y;
    }
    if (lane == 63) wsum[wid] = x;
    __syncthreads();
    if (wid == 0 && lane < 16) {
      unsigned s = wsum[lane];
      #pragma unroll
      for (int d = 1; d < 16; d <<= 1) {
        unsigned y = __shfl_up(s, d, 16);
        if (lane >= d) s += y;
      }
      wsum[lane] = s;
    }
    __syncthreads();
    unsigned wbase = wid ? wsum[wid - 1] : 0u;
    if (i < NN) off[i] = base + wbase + x - v;
    unsigned tot = wsum[15];
    __syncthreads();
    base += tot;
  }
  if (tid == 0) off[NN] = base;
}

__global__ void fill_kernel(const int* __restrict__ src, const int* __restrict__ dst,
                            const unsigned* __restrict__ off, unsigned* __restrict__ cursor,
                            int* __restrict__ edge_src) {
  int e = blockIdx.x * blockDim.x + threadIdx.x;
  if (e < NE) {
    int d = dst[e];
    unsigned p = atomicAdd(&cursor[d], 1u);
    edge_src[off[d] + p] = src[e];
  }
}

// ---------------- weight convert: W[k][n] fp32 -> Wt[n][k] fp16 ----------------
__global__ void convert_w(const float* __restrict__ W0, const float* __restrict__ Ws,
                          _Float16* __restrict__ Wt) {
  int l = blockIdx.z;
  const float* W = (l == 0) ? W0 : (Ws + (size_t)(l - 1) * HF * HF);
  __shared__ float t[32][33];
  int n0 = blockIdx.x * 32, k0 = blockIdx.y * 32;
  int tx = threadIdx.x & 31, ty4 = (threadIdx.x >> 5) * 4;
  #pragma unroll
  for (int j = 0; j < 4; ++j)
    t[ty4 + j][tx] = W[(size_t)(k0 + ty4 + j) * HF + n0 + tx];
  __syncthreads();
  size_t base = (size_t)l * HF * HF;
  #pragma unroll
  for (int j = 0; j < 4; ++j)
    Wt[base + (size_t)(n0 + ty4 + j) * HF + k0 + tx] = (_Float16)t[tx][ty4 + j];
}

// linW[k][c] fp32 -> Lt[c][k] fp16
__global__ void convert_lin(const float* __restrict__ linW, _Float16* __restrict__ Lt) {
  __shared__ float t[32][33];
  int n0 = blockIdx.x * 32, k0 = blockIdx.y * 32;
  int tx = threadIdx.x & 31, ty4 = (threadIdx.x >> 5) * 4;
  #pragma unroll
  for (int j = 0; j < 4; ++j)
    t[ty4 + j][tx] = linW[(size_t)(k0 + ty4 + j) * NC + n0 + tx];
  __syncthreads();
  #pragma unroll
  for (int j = 0; j < 4; ++j)
    Lt[(size_t)(n0 + ty4 + j) * KCAT + k0 + tx] = (_Float16)t[tx][ty4 + j];
}

// ---------------- x*norm_src -> zh fp16 ----------------
__global__ void split_x(const float* __restrict__ x, const float* __restrict__ nsrc,
                        _Float16* __restrict__ zh) {
  int i = blockIdx.x * blockDim.x + threadIdx.x;   // float4 index
  if (i >= NN * HF / 4) return;
  int base = i * 4;
  int row = base >> 9;
  float ns = nsrc[row];
  float4 v = *(const float4*)&x[base];
  f16x4 h;
  h.x = (_Float16)(v.x * ns);
  h.y = (_Float16)(v.y * ns);
  h.z = (_Float16)(v.z * ns);
  h.w = (_Float16)(v.w * ns);
  *(f16x4*)&zh[base] = h;
}

// ---------------- layer GEMM via MFMA, LDS double-buffered 2-phase ----------------
// 128x128 tile, BK=64, 4 waves (2x2), wave tile 64x64 = 4x4 frags of 16x16x32_f16.
// Stage(t+1) issued BEFORE compute(t); one __syncthreads per K-tile.
__launch_bounds__(256, 2)
__global__ void gemm_layer_f16(const _Float16* __restrict__ Z,
                               const _Float16* __restrict__ Wt,
                               _Float16* __restrict__ Mout) {
  __shared__ _Float16 As[2][128][64];
  __shared__ _Float16 Bs[2][128][64];
  int m0 = blockIdx.y * 128;
  int n0 = blockIdx.x * 128;
  int wid = threadIdx.x >> 6, lane = threadIdx.x & 63;
  int wr = wid >> 1, wc = wid & 1;
  int fr = lane & 15, kg = lane >> 4;
  int rr = lane >> 3;            // staging row within 8-row group
  int ck = (lane & 7) ^ rr;      // pre-swizzled source chunk

  f32x4 acc[4][4];
  #pragma unroll
  for (int m = 0; m < 4; ++m)
    #pragma unroll
    for (int n = 0; n < 4; ++n)
      acc[m][n] = (f32x4){0.f, 0.f, 0.f, 0.f};

  const _Float16* gA = Z  + (size_t)(m0 + wid * 32 + rr) * HF + ck * 8;
  const _Float16* gB = Wt + (size_t)(n0 + wid * 32 + rr) * HF + ck * 8;

  auto stage = [&](int buf, int k0) {
    #pragma unroll
    for (int i = 0; i < 4; ++i) {
      __builtin_amdgcn_global_load_lds(GLB(gA + (size_t)i * 8 * HF + k0),
                                       LDSP(&As[buf][wid * 32 + i * 8][0]), 16, 0, 0);
      __builtin_amdgcn_global_load_lds(GLB(gB + (size_t)i * 8 * HF + k0),
                                       LDSP(&Bs[buf][wid * 32 + i * 8][0]), 16, 0, 0);
    }
  };

  stage(0, 0);
  __syncthreads();
  int cur = 0;
  for (int t = 0; t < HF / 64; ++t) {
    if (t < HF / 64 - 1) stage(cur ^ 1, (t + 1) * 64);
    #pragma unroll
    for (int kk = 0; kk < 2; ++kk) {
      f16x8 a[4], b[4];
      #pragma unroll
      for (int n = 0; n < 4; ++n) {
        int row = wc * 64 + n * 16 + fr;
        b[n] = *(const f16x8*)&Bs[cur][row][((kk * 4 + kg) ^ (row & 7)) * 8];
      }
      #pragma unroll
      for (int m = 0; m < 4; ++m) {
        int row = wr * 64 + m * 16 + fr;
        a[m] = *(const f16x8*)&As[cur][row][((kk * 4 + kg) ^ (row & 7)) * 8];
      }
      #pragma unroll
      for (int m = 0; m < 4; ++m)
        #pragma unroll
        for (int n = 0; n < 4; ++n)
          acc[m][n] = __builtin_amdgcn_mfma_f32_16x16x32_f16(a[m], b[n], acc[m][n], 0, 0, 0);
    }
    __syncthreads();
    cur ^= 1;
  }
  // C/D layout: col = lane&15, row = (lane>>4)*4 + j
  #pragma unroll
  for (int m = 0; m < 4; ++m) {
    #pragma unroll
    for (int j = 0; j < 4; ++j) {
      int row = m0 + wr * 64 + m * 16 + kg * 4 + j;
      if (row < NN) {
        #pragma unroll
        for (int n = 0; n < 4; ++n) {
          int col = n0 + wc * 64 + n * 16 + fr;
          Mout[(size_t)row * HF + col] = (_Float16)acc[m][n][j];
        }
      }
    }
  }
}

// ---------------- aggregation + norm_dst + BN(precomputed) + ReLU ----------------
// One 64-lane wave per node, f16x8 (16B) per lane -> one instruction reads a full
// 1KB source row. 4 nodes per 256-thread block; waves independent (no divergence).
__launch_bounds__(256)
__global__ void agg_bn_kernel(const _Float16* __restrict__ Mm,
                              const int* __restrict__ edge_src,
                              const unsigned* __restrict__ row_off,
                              const float* __restrict__ norm_dst,
                              const float* __restrict__ norm_src,
                              const float* __restrict__ bn_scale,  // + l*HF
                              const float* __restrict__ bn_shift,  // + l*HF
                              _Float16* __restrict__ hcat_col,     // hcat + l*HF, stride KCAT
                              _Float16* __restrict__ zh) {         // null on last layer
  int n = blockIdx.x * 4 + (threadIdx.x >> 6);
  if (n >= NN) return;
  int f = (threadIdx.x & 63) * 8;
  unsigned e0 = row_off[n], e1 = row_off[n + 1];
  float a0=0.f,a1=0.f,a2=0.f,a3=0.f,a4=0.f,a5=0.f,a6=0.f,a7=0.f;
  unsigned e = e0;
  for (; e + 4 <= e1; e += 4) {
    int s0 = edge_src[e], s1 = edge_src[e + 1], s2 = edge_src[e + 2], s3 = edge_src[e + 3];
    f16x8 v0 = *(const f16x8*)&Mm[(size_t)s0 * HF + f];
    f16x8 v1 = *(const f16x8*)&Mm[(size_t)s1 * HF + f];
    f16x8 v2 = *(const f16x8*)&Mm[(size_t)s2 * HF + f];
    f16x8 v3 = *(const f16x8*)&Mm[(size_t)s3 * HF + f];
    a0 += (float)v0[0]+(float)v1[0]+(float)v2[0]+(float)v3[0];
    a1 += (float)v0[1]+(float)v1[1]+(float)v2[1]+(float)v3[1];
    a2 += (float)v0[2]+(float)v1[2]+(float)v2[2]+(float)v3[2];
    a3 += (float)v0[3]+(float)v1[3]+(float)v2[3]+(float)v3[3];
    a4 += (float)v0[4]+(float)v1[4]+(float)v2[4]+(float)v3[4];
    a5 += (float)v0[5]+(float)v1[5]+(float)v2[5]+(float)v3[5];
    a6 += (float)v0[6]+(float)v1[6]+(float)v2[6]+(float)v3[6];
    a7 += (float)v0[7]+(float)v1[7]+(float)v2[7]+(float)v3[7];
  }
  for (; e < e1; ++e) {
    int s = edge_src[e];
    f16x8 v = *(const f16x8*)&Mm[(size_t)s * HF + f];
    a0 += (float)v[0]; a1 += (float)v[1]; a2 += (float)v[2]; a3 += (float)v[3];
    a4 += (float)v[4]; a5 += (float)v[5]; a6 += (float)v[6]; a7 += (float)v[7];
  }
  float nd = norm_dst[n];
  float4 s0 = *(const float4*)&bn_scale[f];
  float4 s1 = *(const float4*)&bn_scale[f + 4];
  float4 t0 = *(const float4*)&bn_shift[f];
  float4 t1 = *(const float4*)&bn_shift[f + 4];
  float y0 = fmaxf(fmaf(a0 * nd, s0.x, t0.x), 0.f);
  float y1 = fmaxf(fmaf(a1 * nd, s0.y, t0.y), 0.f);
  float y2 = fmaxf(fmaf(a2 * nd, s0.z, t0.z), 0.f);
  float y3 = fmaxf(fmaf(a3 * nd, s0.w, t0.w), 0.f);
  float y4 = fmaxf(fmaf(a4 * nd, s1.x, t1.x), 0.f);
  float y5 = fmaxf(fmaf(a5 * nd, s1.y, t1.y), 0.f);
  float y6 = fmaxf(fmaf(a6 * nd, s1.z, t1.z), 0.f);
  float y7 = fmaxf(fmaf(a7 * nd, s1.w, t1.w), 0.f);
  f16x8 hv;
  hv[0]=(_Float16)y0; hv[1]=(_Float16)y1; hv[2]=(_Float16)y2; hv[3]=(_Float16)y3;
  hv[4]=(_Float16)y4; hv[5]=(_Float16)y5; hv[6]=(_Float16)y6; hv[7]=(_Float16)y7;
  *(f16x8*)&hcat_col[(size_t)n * KCAT + f] = hv;
  if (zh) {
    float ns = norm_src[n];
    f16x8 zv;
    zv[0]=(_Float16)(y0*ns); zv[1]=(_Float16)(y1*ns); zv[2]=(_Float16)(y2*ns); zv[3]=(_Float16)(y3*ns);
    zv[4]=(_Float16)(y4*ns); zv[5]=(_Float16)(y5*ns); zv[6]=(_Float16)(y6*ns); zv[7]=(_Float16)(y7*ns);
    *(f16x8*)&zh[(size_t)n * HF + f] = zv;
  }
}

// ---------------- final GEMM via MFMA, split-K over 6 chunks, 2-phase dbuf ----------------
__launch_bounds__(256, 2)
__global__ void final_gemm_f16(const _Float16* __restrict__ Hc,
                               const _Float16* __restrict__ Lt,
                               float* __restrict__ part) {
  __shared__ _Float16 As[2][128][64];
  __shared__ _Float16 Bs[2][64][64];
  int m0 = blockIdx.x * 128;
  int sp = blockIdx.y;
  int kbase = sp * HF;
  int wid = threadIdx.x >> 6, lane = threadIdx.x & 63;
  int fr = lane & 15, kg = lane >> 4;
  int rr = lane >> 3;
  int ck = (lane & 7) ^ rr;

  f32x4 acc[2][4];
  #pragma unroll
  for (int m = 0; m < 2; ++m)
    #pragma unroll
    for (int n = 0; n < 4; ++n)
      acc[m][n] = (f32x4){0.f, 0.f, 0.f, 0.f};

  const _Float16* gA = Hc + (size_t)(m0 + wid * 32 + rr) * KCAT + kbase + ck * 8;
  const _Float16* gB = Lt + (size_t)(wid * 16 + rr) * KCAT + kbase + ck * 8;

  auto stage = [&](int buf, int k0) {
    #pragma unroll
    for (int i = 0; i < 4; ++i)
      __builtin_amdgcn_global_load_lds(GLB(gA + (size_t)i * 8 * KCAT + k0),
                                       LDSP(&As[buf][wid * 32 + i * 8][0]), 16, 0, 0);
    #pragma unroll
    for (int i = 0; i < 2; ++i)
      __builtin_amdgcn_global_load_lds(GLB(gB + (size_t)i * 8 * KCAT + k0),
                                       LDSP(&Bs[buf][wid * 16 + i * 8][0]), 16, 0, 0);
  };

  stage(0, 0);
  __syncthreads();
  int cur = 0;
  for (int t = 0; t < HF / 64; ++t) {
    if (t < HF / 64 - 1) stage(cur ^ 1, (t + 1) * 64);
    #pragma unroll
    for (int kk = 0; kk < 2; ++kk) {
      f16x8 a[2], b[4];
      #pragma unroll
      for (int n = 0; n < 4; ++n) {
        int row = n * 16 + fr;
        b[n] = *(const f16x8*)&Bs[cur][row][((kk * 4 + kg) ^ (row & 7)) * 8];
      }
      #pragma unroll
      for (int m = 0; m < 2; ++m) {
        int row = wid * 32 + m * 16 + fr;
        a[m] = *(const f16x8*)&As[cur][row][((kk * 4 + kg) ^ (row & 7)) * 8];
      }
      #pragma unroll
      for (int m = 0; m < 2; ++m)
        #pragma unroll
        for (int n = 0; n < 4; ++n)
          acc[m][n] = __builtin_amdgcn_mfma_f32_16x16x32_f16(a[m], b[n], acc[m][n], 0, 0, 0);
    }
    __syncthreads();
    cur ^= 1;
  }
  #pragma unroll
  for (int m = 0; m < 2; ++m) {
    #pragma unroll
    for (int j = 0; j < 4; ++j) {
      int row = m0 + wid * 32 + m * 16 + kg * 4 + j;
      if (row < NN) {
        #pragma unroll
        for (int n = 0; n < 4; ++n) {
          int col = n * 16 + fr;
          part[((size_t)sp * NN + row) * NC + col] = acc[m][n][j];
        }
      }
    }
  }
}

__launch_bounds__(256)
__global__ void final_reduce(const float* __restrict__ part,
                             const float* __restrict__ linb,
                             float* __restrict__ out) {
  int i = blockIdx.x * blockDim.x + threadIdx.x;   // float4 index
  if (i >= NN * NC / 4) return;
  int n  = i >> 4;
  int cq = i & 15;
  float4 s = *(const float4*)&linb[cq * 4];
  #pragma unroll
  for (int sp = 0; sp < LL; ++sp) {
    float4 v = *(const float4*)&part[((size_t)sp * NN + n) * NC + cq * 4];
    s.x += v.x; s.y += v.y; s.z += v.z; s.w += v.w;
  }
  *(float4*)&out[(size_t)n * NC + cq * 4] = s;
}

// ---------------- launch ----------------

extern "C" void kernel_launch(void* const* d_in, const int* in_sizes, int n_in,
                              void* d_out, int out_size, void* d_ws, size_t ws_size,
                              hipStream_t stream) {
  const float* x     = (const float*)d_in[0];
  const float* W0    = (const float*)d_in[1];
  const float* Ws    = (const float*)d_in[2];
  const float* bs    = (const float*)d_in[3];
  const float* gamma = (const float*)d_in[4];
  const float* beta  = (const float*)d_in[5];
  const float* rmean = (const float*)d_in[6];
  const float* rvar  = (const float*)d_in[7];
  const float* linW  = (const float*)d_in[8];
  const float* linb  = (const float*)d_in[9];
  const int*   src   = (const int*)d_in[10];
  const int*   dst   = (const int*)d_in[11];
  float* out = (float*)d_out;

  char* w = (char*)d_ws;
  size_t o = 0;
  auto carve = [&](size_t bytes) -> void* {
    o = (o + 255) & ~(size_t)255;
    void* p = w + o;
    o += bytes;
    return p;
  };
  _Float16*  m_buf = (_Float16*)carve((size_t)NNPAD * HF * 2);
  _Float16*  hcat  = (_Float16*)carve((size_t)NNPAD * KCAT * 2);
  _Float16*  zh    = (_Float16*)carve((size_t)NNPAD * HF * 2);
  _Float16*  wt    = (_Float16*)carve((size_t)LL * HF * HF * 2);
  _Float16*  lt    = (_Float16*)carve((size_t)NC * KCAT * 2);
  float*     part  = (float*)carve((size_t)LL * NN * NC * 4);
  float*     bnsc  = (float*)carve((size_t)LL * HF * 4);
  float*     bnsh  = (float*)carve((size_t)LL * HF * 4);
  float*     nsrc  = (float*)carve((size_t)NN * 4);
  float*     ndst  = (float*)carve((size_t)NN * 4);
  unsigned*  cnts  = (unsigned*)carve((size_t)3 * NN * 4);
  unsigned*  roff  = (unsigned*)carve((size_t)(NN + 1) * 4);
  int*       esrc  = (int*)carve((size_t)NE * 4);

  unsigned* cnt_out = cnts;
  unsigned* cnt_in  = cnts + NN;
  unsigned* cursor  = cnts + 2 * NN;

  zero_u32_kernel<<<(3 * NN + 255) / 256, 256, 0, stream>>>(cnts, 3 * NN);
  deg_kernel<<<(NE + 255) / 256, 256, 0, stream>>>(src, dst, cnt_out, cnt_in);
  norm_kernel<<<(NN + 255) / 256, 256, 0, stream>>>(cnt_out, cnt_in, nsrc, ndst);
  bn_prep<<<(LL * HF + 255) / 256, 256, 0, stream>>>(bs, gamma, beta, rmean, rvar, bnsc, bnsh);
  scan_kernel<<<1, 1024, 0, stream>>>(cnt_in, roff);
  fill_kernel<<<(NE + 255) / 256, 256, 0, stream>>>(src, dst, roff, cursor, esrc);
  convert_w<<<dim3(16, 16, 6), 256, 0, stream>>>(W0, Ws, wt);
  convert_lin<<<dim3(2, 96), 256, 0, stream>>>(linW, lt);
  split_x<<<(NN * HF / 4 + 255) / 256, 256, 0, stream>>>(x, nsrc, zh);

  for (int l = 0; l < LL; ++l) {
    gemm_layer_f16<<<dim3(HF / 128, NNPAD / 128), 256, 0, stream>>>(
        zh, wt + (size_t)l * HF * HF, m_buf);
    bool last = (l == LL - 1);
    agg_bn_kernel<<<(NN + 3) / 4, 256, 0, stream>>>(m_buf, esrc, roff, ndst, nsrc,
                                                    bnsc + l * HF, bnsh + l * HF,
                                                    hcat + (size_t)l * HF,
                                                    last ? nullptr : zh);
  }
  final_gemm_f16<<<dim3(NNPAD / 128, LL), 256, 0, stream>>>(hcat, lt, part);
  final_reduce<<<(NN * NC / 4 + 255) / 256, 256, 0, stream>>>(part, linb, out);
}

// Round 7
// 285.029 us; speedup vs baseline: 1.1040x; 1.0736x over previous
//
#include <hip/hip_runtime.h>

#define NN 10000      // nodes
#define NNPAD 10112   // padded to 79*128
#define NE 160000     // edges
#define HF 512        // hidden/in features
#define LL 6          // layers
#define NC 64         // classes
#define KCAT (LL*HF)  // 3072
#define BN_EPS 1e-5f

typedef _Float16 f16x8 __attribute__((ext_vector_type(8)));
typedef _Float16 f16x4 __attribute__((ext_vector_type(4)));
typedef float f32x4 __attribute__((ext_vector_type(4)));

#define GLB(p) ((const __attribute__((address_space(1))) void*)(p))
#define LDSP(p) ((__attribute__((address_space(3))) void*)(p))

// ---------------- setup kernels ----------------

__global__ void zero_u32_kernel(unsigned* __restrict__ p, int n) {
  int i = blockIdx.x * blockDim.x + threadIdx.x;
  if (i < n) p[i] = 0u;
}

__global__ void deg_kernel(const int* __restrict__ src, const int* __restrict__ dst,
                           unsigned* __restrict__ cnt_out, unsigned* __restrict__ cnt_in) {
  int e = blockIdx.x * blockDim.x + threadIdx.x;
  if (e < NE) {
    atomicAdd(&cnt_out[src[e]], 1u);
    atomicAdd(&cnt_in[dst[e]], 1u);
  }
}

// merged: degree norms (i<NN) + BN scale/shift (i<LL*HF)
__global__ void prep_kernel(const unsigned* __restrict__ cnt_out, const unsigned* __restrict__ cnt_in,
                            float* __restrict__ norm_src, float* __restrict__ norm_dst,
                            const float* __restrict__ bs, const float* __restrict__ gamma,
                            const float* __restrict__ beta, const float* __restrict__ rmean,
                            const float* __restrict__ rvar,
                            float* __restrict__ scale, float* __restrict__ shift) {
  int i = blockIdx.x * blockDim.x + threadIdx.x;
  if (i < NN) {
    unsigned co = cnt_out[i]; if (co < 1u) co = 1u;
    unsigned ci = cnt_in[i];  if (ci < 1u) ci = 1u;
    norm_src[i] = rsqrtf((float)co);
    norm_dst[i] = rsqrtf((float)ci);
  }
  if (i < LL * HF) {
    float s = gamma[i] * rsqrtf(rvar[i] + BN_EPS);
    scale[i] = s;
    shift[i] = (bs[i] - rmean[i]) * s + beta[i];
  }
}

// exclusive scan of cnt[0..NN) -> off[0..NN], single block of 1024
__global__ void scan_kernel(const unsigned* __restrict__ cnt, unsigned* __restrict__ off) {
  __shared__ unsigned wsum[16];
  int tid = threadIdx.x;
  int lane = tid & 63, wid = tid >> 6;
  unsigned base = 0;
  for (int c = 0; c < NN; c += 1024) {
    int i = c + tid;
    unsigned v = (i < NN) ? cnt[i] : 0u;
    unsigned x = v;
    #pragma unroll
    for (int d = 1; d < 64; d <<= 1) {
      unsigned y = __shfl_up(x, d, 64);
      if (lane >= d) x += y;
    }
    if (lane == 63) wsum[wid] = x;
    __syncthreads();
    if (wid == 0 && lane < 16) {
      unsigned s = wsum[lane];
      #pragma unroll
      for (int d = 1; d < 16; d <<= 1) {
        unsigned y = __shfl_up(s, d, 16);
        if (lane >= d) s += y;
      }
      wsum[lane] = s;
    }
    __syncthreads();
    unsigned wbase = wid ? wsum[wid - 1] : 0u;
    if (i < NN) off[i] = base + wbase + x - v;
    unsigned tot = wsum[15];
    __syncthreads();
    base += tot;
  }
  if (tid == 0) off[NN] = base;
}

__global__ void fill_kernel(const int* __restrict__ src, const int* __restrict__ dst,
                            const unsigned* __restrict__ off, unsigned* __restrict__ cursor,
                            int* __restrict__ edge_src) {
  int e = blockIdx.x * blockDim.x + threadIdx.x;
  if (e < NE) {
    int d = dst[e];
    unsigned p = atomicAdd(&cursor[d], 1u);
    edge_src[off[d] + p] = src[e];
  }
}

// ---------------- weight convert: W[k][n] fp32 -> Wt[n][k] fp16 ----------------
__global__ void convert_w(const float* __restrict__ W0, const float* __restrict__ Ws,
                          _Float16* __restrict__ Wt) {
  int l = blockIdx.z;
  const float* W = (l == 0) ? W0 : (Ws + (size_t)(l - 1) * HF * HF);
  __shared__ float t[32][33];
  int n0 = blockIdx.x * 32, k0 = blockIdx.y * 32;
  int tx = threadIdx.x & 31, ty4 = (threadIdx.x >> 5) * 4;
  #pragma unroll
  for (int j = 0; j < 4; ++j)
    t[ty4 + j][tx] = W[(size_t)(k0 + ty4 + j) * HF + n0 + tx];
  __syncthreads();
  size_t base = (size_t)l * HF * HF;
  #pragma unroll
  for (int j = 0; j < 4; ++j)
    Wt[base + (size_t)(n0 + ty4 + j) * HF + k0 + tx] = (_Float16)t[tx][ty4 + j];
}

// linW[k][c] fp32 -> Lt[c][k] fp16
__global__ void convert_lin(const float* __restrict__ linW, _Float16* __restrict__ Lt) {
  __shared__ float t[32][33];
  int n0 = blockIdx.x * 32, k0 = blockIdx.y * 32;
  int tx = threadIdx.x & 31, ty4 = (threadIdx.x >> 5) * 4;
  #pragma unroll
  for (int j = 0; j < 4; ++j)
    t[ty4 + j][tx] = linW[(size_t)(k0 + ty4 + j) * NC + n0 + tx];
  __syncthreads();
  #pragma unroll
  for (int j = 0; j < 4; ++j)
    Lt[(size_t)(n0 + ty4 + j) * KCAT + k0 + tx] = (_Float16)t[tx][ty4 + j];
}

// ---------------- x -> fp16 (norm_src now applied inside agg) ----------------
__global__ void split_x(const float* __restrict__ x, _Float16* __restrict__ zh) {
  int i = blockIdx.x * blockDim.x + threadIdx.x;   // float4 index
  if (i >= NN * HF / 4) return;
  int base = i * 4;
  float4 v = *(const float4*)&x[base];
  f16x4 h;
  h.x = (_Float16)v.x;
  h.y = (_Float16)v.y;
  h.z = (_Float16)v.z;
  h.w = (_Float16)v.w;
  *(f16x4*)&zh[base] = h;
}

// ---------------- layer GEMM via MFMA, LDS single-buffer (r4-proven) ----------------
// A = Z rows (stride lda: HF for layer0 zh, KCAT for hcat columns); Wt[n][k] fp16.
// 128x128 tile, BK=64, 4 waves (2x2), wave tile 64x64 = 4x4 frags of 16x16x32_f16.
__launch_bounds__(256, 2)
__global__ void gemm_layer_f16(const _Float16* __restrict__ Z, int lda,
                               const _Float16* __restrict__ Wt,
                               _Float16* __restrict__ Mout) {
  __shared__ _Float16 As[128][64];
  __shared__ _Float16 Bs[128][64];
  int m0 = blockIdx.y * 128;
  int n0 = blockIdx.x * 128;
  int wid = threadIdx.x >> 6, lane = threadIdx.x & 63;
  int wr = wid >> 1, wc = wid & 1;
  int fr = lane & 15, kg = lane >> 4;
  int rr = lane >> 3;            // staging row within 8-row group
  int ck = (lane & 7) ^ rr;      // pre-swizzled source chunk

  f32x4 acc[4][4];
  #pragma unroll
  for (int m = 0; m < 4; ++m)
    #pragma unroll
    for (int n = 0; n < 4; ++n)
      acc[m][n] = (f32x4){0.f, 0.f, 0.f, 0.f};

  const _Float16* gA = Z  + (size_t)(m0 + wid * 32 + rr) * lda + ck * 8;
  const _Float16* gB = Wt + (size_t)(n0 + wid * 32 + rr) * HF + ck * 8;

  for (int k0 = 0; k0 < HF; k0 += 64) {
    __syncthreads();
    #pragma unroll
    for (int i = 0; i < 4; ++i) {
      __builtin_amdgcn_global_load_lds(GLB(gA + (size_t)i * 8 * lda + k0),
                                       LDSP(&As[wid * 32 + i * 8][0]), 16, 0, 0);
      __builtin_amdgcn_global_load_lds(GLB(gB + (size_t)i * 8 * HF + k0),
                                       LDSP(&Bs[wid * 32 + i * 8][0]), 16, 0, 0);
    }
    __syncthreads();
    #pragma unroll
    for (int kk = 0; kk < 2; ++kk) {
      f16x8 a[4], b[4];
      #pragma unroll
      for (int n = 0; n < 4; ++n) {
        int row = wc * 64 + n * 16 + fr;
        b[n] = *(const f16x8*)&Bs[row][((kk * 4 + kg) ^ (row & 7)) * 8];
      }
      #pragma unroll
      for (int m = 0; m < 4; ++m) {
        int row = wr * 64 + m * 16 + fr;
        a[m] = *(const f16x8*)&As[row][((kk * 4 + kg) ^ (row & 7)) * 8];
      }
      #pragma unroll
      for (int m = 0; m < 4; ++m)
        #pragma unroll
        for (int n = 0; n < 4; ++n)
          acc[m][n] = __builtin_amdgcn_mfma_f32_16x16x32_f16(a[m], b[n], acc[m][n], 0, 0, 0);
    }
  }
  // C/D layout: col = lane&15, row = (lane>>4)*4 + j
  #pragma unroll
  for (int m = 0; m < 4; ++m) {
    #pragma unroll
    for (int j = 0; j < 4; ++j) {
      int row = m0 + wr * 64 + m * 16 + kg * 4 + j;
      if (row < NN) {
        #pragma unroll
        for (int n = 0; n < 4; ++n) {
          int col = n0 + wc * 64 + n * 16 + fr;
          Mout[(size_t)row * HF + col] = (_Float16)acc[m][n][j];
        }
      }
    }
  }
}

// ---------------- aggregation (with ns[src] row-scale) + norm_dst + BN + ReLU ----------------
// One 64-lane wave per node, f16x8 (16B) per lane -> one instruction per 1KB source row.
// agg[n] = sum_e ns[src_e] * m[src_e]   (row-scaling commuted past the GEMM)
__launch_bounds__(256)
__global__ void agg_bn_kernel(const _Float16* __restrict__ Mm,
                              const int* __restrict__ edge_src,
                              const unsigned* __restrict__ row_off,
                              const float* __restrict__ norm_dst,
                              const float* __restrict__ norm_src,
                              const float* __restrict__ bn_scale,  // + l*HF
                              const float* __restrict__ bn_shift,  // + l*HF
                              _Float16* __restrict__ hcat_col) {   // hcat + l*HF, stride KCAT
  int n = blockIdx.x * 4 + (threadIdx.x >> 6);
  if (n >= NN) return;
  int f = (threadIdx.x & 63) * 8;
  unsigned e0 = row_off[n], e1 = row_off[n + 1];
  float a0=0.f,a1=0.f,a2=0.f,a3=0.f,a4=0.f,a5=0.f,a6=0.f,a7=0.f;
  unsigned e = e0;
  for (; e + 4 <= e1; e += 4) {
    int s0 = edge_src[e], s1 = edge_src[e + 1], s2 = edge_src[e + 2], s3 = edge_src[e + 3];
    float n0 = norm_src[s0], n1 = norm_src[s1], n2 = norm_src[s2], n3 = norm_src[s3];
    f16x8 v0 = *(const f16x8*)&Mm[(size_t)s0 * HF + f];
    f16x8 v1 = *(const f16x8*)&Mm[(size_t)s1 * HF + f];
    f16x8 v2 = *(const f16x8*)&Mm[(size_t)s2 * HF + f];
    f16x8 v3 = *(const f16x8*)&Mm[(size_t)s3 * HF + f];
    a0 = fmaf((float)v0[0], n0, fmaf((float)v1[0], n1, fmaf((float)v2[0], n2, fmaf((float)v3[0], n3, a0))));
    a1 = fmaf((float)v0[1], n0, fmaf((float)v1[1], n1, fmaf((float)v2[1], n2, fmaf((float)v3[1], n3, a1))));
    a2 = fmaf((float)v0[2], n0, fmaf((float)v1[2], n1, fmaf((float)v2[2], n2, fmaf((float)v3[2], n3, a2))));
    a3 = fmaf((float)v0[3], n0, fmaf((float)v1[3], n1, fmaf((float)v2[3], n2, fmaf((float)v3[3], n3, a3))));
    a4 = fmaf((float)v0[4], n0, fmaf((float)v1[4], n1, fmaf((float)v2[4], n2, fmaf((float)v3[4], n3, a4))));
    a5 = fmaf((float)v0[5], n0, fmaf((float)v1[5], n1, fmaf((float)v2[5], n2, fmaf((float)v3[5], n3, a5))));
    a6 = fmaf((float)v0[6], n0, fmaf((float)v1[6], n1, fmaf((float)v2[6], n2, fmaf((float)v3[6], n3, a6))));
    a7 = fmaf((float)v0[7], n0, fmaf((float)v1[7], n1, fmaf((float)v2[7], n2, fmaf((float)v3[7], n3, a7))));
  }
  for (; e < e1; ++e) {
    int s = edge_src[e];
    float ns = norm_src[s];
    f16x8 v = *(const f16x8*)&Mm[(size_t)s * HF + f];
    a0 = fmaf((float)v[0], ns, a0); a1 = fmaf((float)v[1], ns, a1);
    a2 = fmaf((float)v[2], ns, a2); a3 = fmaf((float)v[3], ns, a3);
    a4 = fmaf((float)v[4], ns, a4); a5 = fmaf((float)v[5], ns, a5);
    a6 = fmaf((float)v[6], ns, a6); a7 = fmaf((float)v[7], ns, a7);
  }
  float nd = norm_dst[n];
  float4 s0 = *(const float4*)&bn_scale[f];
  float4 s1 = *(const float4*)&bn_scale[f + 4];
  float4 t0 = *(const float4*)&bn_shift[f];
  float4 t1 = *(const float4*)&bn_shift[f + 4];
  float y0 = fmaxf(fmaf(a0 * nd, s0.x, t0.x), 0.f);
  float y1 = fmaxf(fmaf(a1 * nd, s0.y, t0.y), 0.f);
  float y2 = fmaxf(fmaf(a2 * nd, s0.z, t0.z), 0.f);
  float y3 = fmaxf(fmaf(a3 * nd, s0.w, t0.w), 0.f);
  float y4 = fmaxf(fmaf(a4 * nd, s1.x, t1.x), 0.f);
  float y5 = fmaxf(fmaf(a5 * nd, s1.y, t1.y), 0.f);
  float y6 = fmaxf(fmaf(a6 * nd, s1.z, t1.z), 0.f);
  float y7 = fmaxf(fmaf(a7 * nd, s1.w, t1.w), 0.f);
  f16x8 hv;
  hv[0]=(_Float16)y0; hv[1]=(_Float16)y1; hv[2]=(_Float16)y2; hv[3]=(_Float16)y3;
  hv[4]=(_Float16)y4; hv[5]=(_Float16)y5; hv[6]=(_Float16)y6; hv[7]=(_Float16)y7;
  *(f16x8*)&hcat_col[(size_t)n * KCAT + f] = hv;
}

// ---------------- final GEMM via MFMA, split-K over 6 chunks, single-buffer ----------------
__launch_bounds__(256, 2)
__global__ void final_gemm_f16(const _Float16* __restrict__ Hc,
                               const _Float16* __restrict__ Lt,
                               float* __restrict__ part) {
  __shared__ _Float16 As[128][64];
  __shared__ _Float16 Bs[64][64];
  int m0 = blockIdx.x * 128;
  int sp = blockIdx.y;
  int kbase = sp * HF;
  int wid = threadIdx.x >> 6, lane = threadIdx.x & 63;
  int fr = lane & 15, kg = lane >> 4;
  int rr = lane >> 3;
  int ck = (lane & 7) ^ rr;

  f32x4 acc[2][4];
  #pragma unroll
  for (int m = 0; m < 2; ++m)
    #pragma unroll
    for (int n = 0; n < 4; ++n)
      acc[m][n] = (f32x4){0.f, 0.f, 0.f, 0.f};

  const _Float16* gA = Hc + (size_t)(m0 + wid * 32 + rr) * KCAT + kbase + ck * 8;
  const _Float16* gB = Lt + (size_t)(wid * 16 + rr) * KCAT + kbase + ck * 8;

  for (int k0 = 0; k0 < HF; k0 += 64) {
    __syncthreads();
    #pragma unroll
    for (int i = 0; i < 4; ++i)
      __builtin_amdgcn_global_load_lds(GLB(gA + (size_t)i * 8 * KCAT + k0),
                                       LDSP(&As[wid * 32 + i * 8][0]), 16, 0, 0);
    #pragma unroll
    for (int i = 0; i < 2; ++i)
      __builtin_amdgcn_global_load_lds(GLB(gB + (size_t)i * 8 * KCAT + k0),
                                       LDSP(&Bs[wid * 16 + i * 8][0]), 16, 0, 0);
    __syncthreads();
    #pragma unroll
    for (int kk = 0; kk < 2; ++kk) {
      f16x8 a[2], b[4];
      #pragma unroll
      for (int n = 0; n < 4; ++n) {
        int row = n * 16 + fr;
        b[n] = *(const f16x8*)&Bs[row][((kk * 4 + kg) ^ (row & 7)) * 8];
      }
      #pragma unroll
      for (int m = 0; m < 2; ++m) {
        int row = wid * 32 + m * 16 + fr;
        a[m] = *(const f16x8*)&As[row][((kk * 4 + kg) ^ (row & 7)) * 8];
      }
      #pragma unroll
      for (int m = 0; m < 2; ++m)
        #pragma unroll
        for (int n = 0; n < 4; ++n)
          acc[m][n] = __builtin_amdgcn_mfma_f32_16x16x32_f16(a[m], b[n], acc[m][n], 0, 0, 0);
    }
  }
  #pragma unroll
  for (int m = 0; m < 2; ++m) {
    #pragma unroll
    for (int j = 0; j < 4; ++j) {
      int row = m0 + wid * 32 + m * 16 + kg * 4 + j;
      if (row < NN) {
        #pragma unroll
        for (int n = 0; n < 4; ++n) {
          int col = n * 16 + fr;
          part[((size_t)sp * NN + row) * NC + col] = acc[m][n][j];
        }
      }
    }
  }
}

__launch_bounds__(256)
__global__ void final_reduce(const float* __restrict__ part,
                             const float* __restrict__ linb,
                             float* __restrict__ out) {
  int i = blockIdx.x * blockDim.x + threadIdx.x;   // float4 index
  if (i >= NN * NC / 4) return;
  int n  = i >> 4;
  int cq = i & 15;
  float4 s = *(const float4*)&linb[cq * 4];
  #pragma unroll
  for (int sp = 0; sp < LL; ++sp) {
    float4 v = *(const float4*)&part[((size_t)sp * NN + n) * NC + cq * 4];
    s.x += v.x; s.y += v.y; s.z += v.z; s.w += v.w;
  }
  *(float4*)&out[(size_t)n * NC + cq * 4] = s;
}

// ---------------- launch ----------------

extern "C" void kernel_launch(void* const* d_in, const int* in_sizes, int n_in,
                              void* d_out, int out_size, void* d_ws, size_t ws_size,
                              hipStream_t stream) {
  const float* x     = (const float*)d_in[0];
  const float* W0    = (const float*)d_in[1];
  const float* Ws    = (const float*)d_in[2];
  const float* bs    = (const float*)d_in[3];
  const float* gamma = (const float*)d_in[4];
  const float* beta  = (const float*)d_in[5];
  const float* rmean = (const float*)d_in[6];
  const float* rvar  = (const float*)d_in[7];
  const float* linW  = (const float*)d_in[8];
  const float* linb  = (const float*)d_in[9];
  const int*   src   = (const int*)d_in[10];
  const int*   dst   = (const int*)d_in[11];
  float* out = (float*)d_out;

  char* w = (char*)d_ws;
  size_t o = 0;
  auto carve = [&](size_t bytes) -> void* {
    o = (o + 255) & ~(size_t)255;
    void* p = w + o;
    o += bytes;
    return p;
  };
  _Float16*  m_buf = (_Float16*)carve((size_t)NNPAD * HF * 2);
  _Float16*  hcat  = (_Float16*)carve((size_t)NNPAD * KCAT * 2);
  _Float16*  zh    = (_Float16*)carve((size_t)NNPAD * HF * 2);   // layer-0 input only
  _Float16*  wt    = (_Float16*)carve((size_t)LL * HF * HF * 2);
  _Float16*  lt    = (_Float16*)carve((size_t)NC * KCAT * 2);
  float*     part  = (float*)carve((size_t)LL * NN * NC * 4);
  float*     bnsc  = (float*)carve((size_t)LL * HF * 4);
  float*     bnsh  = (float*)carve((size_t)LL * HF * 4);
  float*     nsrc  = (float*)carve((size_t)NN * 4);
  float*     ndst  = (float*)carve((size_t)NN * 4);
  unsigned*  cnts  = (unsigned*)carve((size_t)3 * NN * 4);
  unsigned*  roff  = (unsigned*)carve((size_t)(NN + 1) * 4);
  int*       esrc  = (int*)carve((size_t)NE * 4);

  unsigned* cnt_out = cnts;
  unsigned* cnt_in  = cnts + NN;
  unsigned* cursor  = cnts + 2 * NN;

  zero_u32_kernel<<<(3 * NN + 255) / 256, 256, 0, stream>>>(cnts, 3 * NN);
  deg_kernel<<<(NE + 255) / 256, 256, 0, stream>>>(src, dst, cnt_out, cnt_in);
  prep_kernel<<<(NN + 255) / 256, 256, 0, stream>>>(cnt_out, cnt_in, nsrc, ndst,
                                                    bs, gamma, beta, rmean, rvar, bnsc, bnsh);
  scan_kernel<<<1, 1024, 0, stream>>>(cnt_in, roff);
  fill_kernel<<<(NE + 255) / 256, 256, 0, stream>>>(src, dst, roff, cursor, esrc);
  convert_w<<<dim3(16, 16, 6), 256, 0, stream>>>(W0, Ws, wt);
  convert_lin<<<dim3(2, 96), 256, 0, stream>>>(linW, lt);
  split_x<<<(NN * HF / 4 + 255) / 256, 256, 0, stream>>>(x, zh);

  for (int l = 0; l < LL; ++l) {
    const _Float16* A   = (l == 0) ? zh : (hcat + (size_t)(l - 1) * HF);
    int             lda = (l == 0) ? HF : KCAT;
    gemm_layer_f16<<<dim3(HF / 128, NNPAD / 128), 256, 0, stream>>>(
        A, lda, wt + (size_t)l * HF * HF, m_buf);
    agg_bn_kernel<<<(NN + 3) / 4, 256, 0, stream>>>(m_buf, esrc, roff, ndst, nsrc,
                                                    bnsc + l * HF, bnsh + l * HF,
                                                    hcat + (size_t)l * HF);
  }
  final_gemm_f16<<<dim3(NNPAD / 128, LL), 256, 0, stream>>>(hcat, lt, part);
  final_reduce<<<(NN * NC / 4 + 255) / 256, 256, 0, stream>>>(part, linb, out);
}